// Round 4
// baseline (120.902 us; speedup 1.0000x reference)
//
#include <hip/hip_runtime.h>
#include <hip/hip_bf16.h>

// Problem constants
#define BATCH 4
#define S_TOT 4096
#define ROWS (BATCH * S_TOT)   // 16384
#define DM 2048
#define DSP 128
#define NSEG 512               // neurons per segment; 3 segments

typedef short short8 __attribute__((ext_vector_type(8)));
typedef float f32x16 __attribute__((ext_vector_type(16)));

// float -> bf16(RNE) bits; also returns the fp32 value of the bf16 for residual
static __device__ inline short f2bf(float v, float& back) {
  unsigned u = __float_as_uint(v);
  unsigned r = u + 0x7FFFu + ((u >> 16) & 1u);
  unsigned short hs = (unsigned short)(r >> 16);
  back = __uint_as_float(((unsigned)hs) << 16);
  return (short)hs;
}

// Fragment layout for a [R][128-k] matrix, per split:
//   short8 index = rowblk*512 + kchunk*64 + lane,  lane=(row&31)+32*((k>>3)&1)
// For W (B-operand, [128 n][2048 k]): short8 index = (tile*128 + kchunk)*64 + lane,
//   lane=(n&31)+32*((k>>3)&1), tile=n>>5.

// ---------------- K0 fused: W-split pack (blocks 0..511) + emb norm pack -------
__global__ __launch_bounds__(64) void k0_prep(const float* __restrict__ W,
                                              const float* __restrict__ emb,
                                              short* __restrict__ wHi,
                                              short* __restrict__ wLo,
                                              short* __restrict__ eHi,
                                              short* __restrict__ eLo) {
  const int l = threadIdx.x;
  if (blockIdx.x < 512) {
    // pack W: blockIdx = tile*128 + kchunk
    const int tc = blockIdx.x;
    const int t = tc >> 7, c = tc & 127;
    const int n = t * 32 + (l & 31);
    const int k = c * 16 + (l >> 5) * 8;
    const float4 a0 = *(const float4*)&W[(size_t)n * DM + k];
    const float4 a1 = *(const float4*)&W[(size_t)n * DM + k + 4];
    const float av[8] = {a0.x, a0.y, a0.z, a0.w, a1.x, a1.y, a1.z, a1.w};
    short8 hi8, lo8; float bk;
    #pragma unroll
    for (int e = 0; e < 8; ++e) {
      hi8[e] = f2bf(av[e], bk); lo8[e] = f2bf(av[e] - bk, bk);
    }
    const size_t idx = (size_t)tc * 64 + l;
    ((short8*)wHi)[idx] = hi8;
    ((short8*)wLo)[idx] = lo8;
  } else {
    // normalize + pack one emb row
    const int row = blockIdx.x - 512;          // 0..1535
    __shared__ short sh[128], sl[128];
    float2 v = *(const float2*)&emb[row * 128 + l * 2];
    float ss = v.x * v.x + v.y * v.y;
    #pragma unroll
    for (int m = 32; m; m >>= 1) ss += __shfl_xor(ss, m);
    const float inv = 1.0f / fmaxf(sqrtf(ss), 1e-12f);
    float bk;
    const float ox = v.x * inv, oy = v.y * inv;
    sh[2 * l] = f2bf(ox, bk);     sl[2 * l] = f2bf(ox - bk, bk);
    sh[2 * l + 1] = f2bf(oy, bk); sl[2 * l + 1] = f2bf(oy - bk, bk);
    __syncthreads();
    if (l < 32) {
      const int split = l >> 4, kc = (l >> 1) & 7, kh = l & 1;
      const short* src = (split ? sl : sh) + kc * 16 + kh * 8;
      const short8 val = *(const short8*)src;
      const size_t idx = (size_t)(row >> 5) * 4096 + kc * 512 +
                         ((row & 31) + 32 * kh) * 8;
      *(short8*)((split ? eLo : eHi) + idx) = val;
    }
  }
}

// ---------------- K1: h = x @ W^T + b, fused split+pack, no main-loop LDS ------
// grid 512 (32-row tiles), 256 threads = 4 waves = 4 K-quarters.
// Wave: lane fr=row, ks=k-subgroup; A direct from global x (convert in-reg);
// B from packed wHi/wLo (L2). Epilogue: 2-barrier LDS reduce + bias + pack.
__global__ __launch_bounds__(256, 3) void k1_fused(const float* __restrict__ x,
                                                   const short* __restrict__ wHi,
                                                   const short* __restrict__ wLo,
                                                   const float* __restrict__ bias,
                                                   short* __restrict__ hHi,
                                                   short* __restrict__ hLo) {
  __shared__ __align__(16) float hsA[32][132];
  __shared__ __align__(16) float hsB[32][132];
  __shared__ float bsh[128];
  const int t = threadIdx.x;
  const int wave = t >> 6, lane = t & 63;
  const int fr = lane & 31, ks = lane >> 5;
  const int m0 = blockIdx.x * 32;

  if (t < 128) bsh[t] = bias[t];

  const float* xp = x + (size_t)(m0 + fr) * DM + wave * 512 + ks * 8;
  const short8* bhp = (const short8*)wHi;
  const short8* blp = (const short8*)wLo;

  f32x16 acc[4] = {};

  #pragma unroll 2
  for (int c = 0; c < 32; ++c) {
    const int cc = wave * 32 + c;                 // global 16-k chunk
    const float4 a0 = *(const float4*)(xp + c * 16);
    const float4 a1 = *(const float4*)(xp + c * 16 + 4);
    const float av[8] = {a0.x, a0.y, a0.z, a0.w, a1.x, a1.y, a1.z, a1.w};
    short8 ah, al; float bk;
    #pragma unroll
    for (int e = 0; e < 8; ++e) {
      ah[e] = f2bf(av[e], bk); al[e] = f2bf(av[e] - bk, bk);
    }
    const short8* bb = bhp + (size_t)cc * 64 + lane;
    const short8* bb2 = blp + (size_t)cc * 64 + lane;
    #pragma unroll
    for (int t2 = 0; t2 < 4; ++t2) {
      const short8 bh = bb[t2 * 8192];
      const short8 bl = bb2[t2 * 8192];
      acc[t2] = __builtin_amdgcn_mfma_f32_32x32x16_bf16(ah, bh, acc[t2], 0, 0, 0);
      acc[t2] = __builtin_amdgcn_mfma_f32_32x32x16_bf16(ah, bl, acc[t2], 0, 0, 0);
      acc[t2] = __builtin_amdgcn_mfma_f32_32x32x16_bf16(al, bh, acc[t2], 0, 0, 0);
    }
  }

  // ---- cross-wave K-reduction: waves 0,1 write; waves 2,3 add ----
  if (wave == 0 || wave == 1) {
    float (*hs)[132] = wave ? hsB : hsA;
    #pragma unroll
    for (int t2 = 0; t2 < 4; ++t2)
      #pragma unroll
      for (int reg = 0; reg < 16; ++reg) {
        const int row = (reg & 3) + 8 * (reg >> 2) + 4 * ks;
        hs[row][t2 * 32 + fr] = acc[t2][reg];
      }
  }
  __syncthreads();
  if (wave == 2 || wave == 3) {
    float (*hs)[132] = (wave == 3) ? hsB : hsA;
    #pragma unroll
    for (int t2 = 0; t2 < 4; ++t2)
      #pragma unroll
      for (int reg = 0; reg < 16; ++reg) {
        const int row = (reg & 3) + 8 * (reg >> 2) + 4 * ks;
        hs[row][t2 * 32 + fr] += acc[t2][reg];
      }
  }
  __syncthreads();

  // ---- pack: 512 tasks (row, 8k-group), 2 per thread ----
  #pragma unroll
  for (int i = 0; i < 2; ++i) {
    const int task = t + 256 * i;
    const int row = task >> 4, kc8 = task & 15;
    const float4 va = *(const float4*)&hsA[row][kc8 * 8];
    const float4 vb = *(const float4*)&hsA[row][kc8 * 8 + 4];
    const float4 wa = *(const float4*)&hsB[row][kc8 * 8];
    const float4 wb = *(const float4*)&hsB[row][kc8 * 8 + 4];
    const float4 ba = *(const float4*)&bsh[kc8 * 8];
    const float4 bb4 = *(const float4*)&bsh[kc8 * 8 + 4];
    const float v[8] = {va.x + wa.x + ba.x, va.y + wa.y + ba.y,
                        va.z + wa.z + ba.z, va.w + wa.w + ba.w,
                        vb.x + wb.x + bb4.x, vb.y + wb.y + bb4.y,
                        vb.z + wb.z + bb4.z, vb.w + wb.w + bb4.w};
    short8 hi8, lo8; float bk;
    #pragma unroll
    for (int e = 0; e < 8; ++e) {
      hi8[e] = f2bf(v[e], bk); lo8[e] = f2bf(v[e] - bk, bk);
    }
    const int kc = kc8 >> 1, kh = kc8 & 1;
    const size_t idx = (size_t)blockIdx.x * 512 + kc * 64 + (row + 32 * kh);
    ((short8*)hHi)[idx] = hi8;
    ((short8*)hLo)[idx] = lo8;
  }
}

// ---------------- K2: logits via MFMA + softmax + weighted col-sum -------------
// grid (256 row-tiles of 64, 3 segments), 512 threads = 8 waves. (verified)
__global__ __launch_bounds__(512, 2) void k2_mfma(const short* __restrict__ hHi,
                                                  const short* __restrict__ hLo,
                                                  const short* __restrict__ eHi,
                                                  const short* __restrict__ eLo,
                                                  const float* __restrict__ imp,
                                                  float* __restrict__ partials) {
  const int t = threadIdx.x;
  const int m0 = blockIdx.x * 64;
  const int seg = blockIdx.y;
  const int wave = t >> 6, lane = t & 63;
  const int wr = wave >> 2;
  const int wc = wave & 3;
  const int fr = lane & 31;
  const int hi = lane >> 5;

  __shared__ float redA[2][32][4];
  __shared__ float redB[2][32][4];
  __shared__ float ldsD[2][512];

  f32x16 acc[4] = {};

  const short8* pAh = (const short8*)hHi + ((m0 >> 5) + wr) * 512 + lane;
  const short8* pAl = (const short8*)hLo + ((m0 >> 5) + wr) * 512 + lane;
  const short8* pBh = (const short8*)eHi + (seg * 16 + wc * 4) * 512 + lane;
  const short8* pBl = (const short8*)eLo + (seg * 16 + wc * 4) * 512 + lane;

  #pragma unroll
  for (int kc = 0; kc < 8; ++kc) {
    const short8 ah = pAh[kc * 64];
    const short8 al = pAl[kc * 64];
    #pragma unroll
    for (int t2 = 0; t2 < 4; ++t2) {
      const short8 bh = pBh[t2 * 512 + kc * 64];
      const short8 bl = pBl[t2 * 512 + kc * 64];
      acc[t2] = __builtin_amdgcn_mfma_f32_32x32x16_bf16(ah, bh, acc[t2], 0, 0, 0);
      acc[t2] = __builtin_amdgcn_mfma_f32_32x32x16_bf16(ah, bl, acc[t2], 0, 0, 0);
      acc[t2] = __builtin_amdgcn_mfma_f32_32x32x16_bf16(al, bh, acc[t2], 0, 0, 0);
    }
  }

  // ---- row max (over 512 neurons) ----
  float mx[16];
  #pragma unroll
  for (int r = 0; r < 16; ++r) {
    float m = fmaxf(fmaxf(acc[0][r], acc[1][r]), fmaxf(acc[2][r], acc[3][r]));
    #pragma unroll
    for (int k = 1; k < 32; k <<= 1) m = fmaxf(m, __shfl_xor(m, k));
    mx[r] = m;
  }
  if (fr == 0) {
    #pragma unroll
    for (int r = 0; r < 16; ++r)
      redA[wr][(r & 3) + 8 * (r >> 2) + 4 * hi][wc] = mx[r];
  }
  __syncthreads();
  float M[16];
  #pragma unroll
  for (int r = 0; r < 16; ++r) {
    const int row = (r & 3) + 8 * (r >> 2) + 4 * hi;
    M[r] = fmaxf(fmaxf(redA[wr][row][0], redA[wr][row][1]),
                 fmaxf(redA[wr][row][2], redA[wr][row][3]));
  }

  // ---- exp + row sum ----
  float sm[16];
  #pragma unroll
  for (int r = 0; r < 16; ++r) {
    float s = 0.0f;
    #pragma unroll
    for (int t2 = 0; t2 < 4; ++t2) {
      const float p = __expf(acc[t2][r] - M[r]);
      acc[t2][r] = p;
      s += p;
    }
    #pragma unroll
    for (int k = 1; k < 32; k <<= 1) s += __shfl_xor(s, k);
    sm[r] = s;
  }
  if (fr == 0) {
    #pragma unroll
    for (int r = 0; r < 16; ++r)
      redB[wr][(r & 3) + 8 * (r >> 2) + 4 * hi][wc] = sm[r];
  }
  __syncthreads();
  float w[16];
  #pragma unroll
  for (int r = 0; r < 16; ++r) {
    const int row = (r & 3) + 8 * (r >> 2) + 4 * hi;
    const float S = (redB[wr][row][0] + redB[wr][row][1]) +
                    (redB[wr][row][2] + redB[wr][row][3]);
    w[r] = imp[m0 + wr * 32 + row] / S;
  }

  // ---- importance-weighted column partials (deterministic) ----
  #pragma unroll
  for (int t2 = 0; t2 < 4; ++t2) {
    float d = 0.0f;
    #pragma unroll
    for (int r = 0; r < 16; ++r) d = fmaf(acc[t2][r], w[r], d);
    d += __shfl_xor(d, 32);
    if (hi == 0) ldsD[wr][wc * 128 + t2 * 32 + fr] = d;
  }
  __syncthreads();
  partials[((size_t)seg * 256 + blockIdx.x) * 512 + t] = ldsD[0][t] + ldsD[1][t];
}

// ---------------- K3: sum partials (fixed order) + top-k + write ---------------
__global__ __launch_bounds__(256) void k3_topk(const float* __restrict__ partials,
                                               float* __restrict__ out) {
  const int b = blockIdx.x;
  const int seg = blockIdx.y;
  const int tid = threadIdx.x;
  const int K = (seg == 0) ? 8 : ((seg == 1) ? 4 : 6);

  __shared__ float v[512];
  __shared__ float wv[8];
  __shared__ int wi[8];
  __shared__ float redv[4];
  __shared__ int redi[4];

  const float* src = partials + ((size_t)seg * 256 + b * 64) * 512;
  float a0 = 0.f, a1 = 0.f, a2 = 0.f, a3 = 0.f;
  float b0 = 0.f, b1 = 0.f, b2 = 0.f, b3 = 0.f;
  for (int j = 0; j < 64; j += 4) {
    a0 += src[(size_t)(j + 0) * 512 + tid];
    a1 += src[(size_t)(j + 1) * 512 + tid];
    a2 += src[(size_t)(j + 2) * 512 + tid];
    a3 += src[(size_t)(j + 3) * 512 + tid];
    b0 += src[(size_t)(j + 0) * 512 + tid + 256];
    b1 += src[(size_t)(j + 1) * 512 + tid + 256];
    b2 += src[(size_t)(j + 2) * 512 + tid + 256];
    b3 += src[(size_t)(j + 3) * 512 + tid + 256];
  }
  v[tid] = (a0 + a1) + (a2 + a3);
  v[tid + 256] = (b0 + b1) + (b2 + b3);
  __syncthreads();

  for (int t = 0; t < K; ++t) {
    const float v0 = v[tid], v1 = v[tid + 256];
    float bv; int bi;
    if (v1 > v0) { bv = v1; bi = tid + 256; } else { bv = v0; bi = tid; }
    #pragma unroll
    for (int m = 1; m < 64; m <<= 1) {
      const float ov = __shfl_xor(bv, m);
      const int oi = __shfl_xor(bi, m);
      if (ov > bv || (ov == bv && oi < bi)) { bv = ov; bi = oi; }
    }
    if ((tid & 63) == 0) { redv[tid >> 6] = bv; redi[tid >> 6] = bi; }
    __syncthreads();
    if (tid == 0) {
      float best = redv[0]; int besti = redi[0];
      for (int q = 1; q < 4; ++q)
        if (redv[q] > best || (redv[q] == best && redi[q] < besti)) {
          best = redv[q]; besti = redi[q];
        }
      wv[t] = best; wi[t] = besti;
      v[besti] = -3.0e38f;
    }
    __syncthreads();
  }

  float s = 1e-8f;
  for (int t = 0; t < K; ++t) s += wv[t];

  const int slot0 = (seg == 0) ? 0 : ((seg == 1) ? 1 : 3);
  float* o0 = out + slot0 * (BATCH * NSEG) + b * NSEG;
  o0[tid] = 0.0f; o0[tid + 256] = 0.0f;
  float* o1 = nullptr;
  if (seg == 1) {
    o1 = out + 2 * (BATCH * NSEG) + b * NSEG;
    o1[tid] = 0.0f; o1[tid + 256] = 0.0f;
  }
  __syncthreads();
  if (tid < K) {
    const float val = wv[tid] / s;
    o0[wi[tid]] = val;
    if (seg == 1) o1[wi[tid]] = val;
  }
}

// -------------------------------- launch ---------------------------------------
extern "C" void kernel_launch(void* const* d_in, const int* in_sizes, int n_in,
                              void* d_out, int out_size, void* d_ws, size_t ws_size,
                              hipStream_t stream) {
  (void)in_sizes; (void)n_in; (void)out_size; (void)ws_size;
  const float* x    = (const float*)d_in[0];
  const float* imp  = (const float*)d_in[1];
  const float* W    = (const float*)d_in[2];
  const float* bias = (const float*)d_in[3];
  const float* emb  = (const float*)d_in[4];
  float* out = (float*)d_out;

  // workspace carve: partials (f32), then hHi | hLo | eHi | eLo | wHi | wLo (i16)
  float* partials = (float*)d_ws;                     // 768*512 f32
  short* hHi      = (short*)(partials + 768 * 512);   // 2097152 i16
  short* hLo      = hHi + 2097152;
  short* eHi      = hLo + 2097152;                    // 196608 i16
  short* eLo      = eHi + 196608;
  short* wHi      = eLo + 196608;                     // 262144 i16
  short* wLo      = wHi + 262144;

  k0_prep<<<512 + 1536, 64, 0, stream>>>(W, emb, wHi, wLo, eHi, eLo);
  k1_fused<<<ROWS / 32, 256, 0, stream>>>(x, wHi, wLo, bias, hHi, hLo);
  k2_mfma<<<dim3(ROWS / 64, 3), 512, 0, stream>>>(hHi, hLo, eHi, eLo, imp, partials);
  k3_topk<<<dim3(BATCH, 3), 256, 0, stream>>>(partials, out);
}

// Round 5
// 104.271 us; speedup vs baseline: 1.1595x; 1.1595x over previous
//
#include <hip/hip_runtime.h>
#include <hip/hip_bf16.h>

// Problem constants
#define BATCH 4
#define S_TOT 4096
#define ROWS (BATCH * S_TOT)   // 16384
#define DM 2048
#define DSP 128
#define NSEG 512               // neurons per segment; 3 segments

typedef short short8 __attribute__((ext_vector_type(8)));
typedef float f32x16 __attribute__((ext_vector_type(16)));

// float -> bf16(RNE) bits; also returns the fp32 value of the bf16 for residual
static __device__ inline short f2bf(float v, float& back) {
  unsigned u = __float_as_uint(v);
  unsigned r = u + 0x7FFFu + ((u >> 16) & 1u);
  unsigned short hs = (unsigned short)(r >> 16);
  back = __uint_as_float(((unsigned)hs) << 16);
  return (short)hs;
}

// Fragment layout for a [R][128-k] matrix, per split:
//   short8 index = rowblk*512 + kchunk*64 + lane,  lane=(row&31)+32*((k>>3)&1)
// For W (B-operand, [128 n][2048 k]): short8 index = (tile*128 + kchunk)*64 + lane,
//   lane=(n&31)+32*((k>>3)&1), tile=n>>5.

// ---------------- K0 fused: W-split pack (blocks 0..511) + emb norm pack -------
__global__ __launch_bounds__(64) void k0_prep(const float* __restrict__ W,
                                              const float* __restrict__ emb,
                                              short* __restrict__ wHi,
                                              short* __restrict__ wLo,
                                              short* __restrict__ eHi,
                                              short* __restrict__ eLo) {
  const int l = threadIdx.x;
  if (blockIdx.x < 512) {
    // pack W: blockIdx = tile*128 + kchunk
    const int tc = blockIdx.x;
    const int t = tc >> 7, c = tc & 127;
    const int n = t * 32 + (l & 31);
    const int k = c * 16 + (l >> 5) * 8;
    const float4 a0 = *(const float4*)&W[(size_t)n * DM + k];
    const float4 a1 = *(const float4*)&W[(size_t)n * DM + k + 4];
    const float av[8] = {a0.x, a0.y, a0.z, a0.w, a1.x, a1.y, a1.z, a1.w};
    short8 hi8, lo8; float bk;
    #pragma unroll
    for (int e = 0; e < 8; ++e) {
      hi8[e] = f2bf(av[e], bk); lo8[e] = f2bf(av[e] - bk, bk);
    }
    const size_t idx = (size_t)tc * 64 + l;
    ((short8*)wHi)[idx] = hi8;
    ((short8*)wLo)[idx] = lo8;
  } else {
    // normalize + pack one emb row
    const int row = blockIdx.x - 512;          // 0..1535
    __shared__ short sh[128], sl[128];
    float2 v = *(const float2*)&emb[row * 128 + l * 2];
    float ss = v.x * v.x + v.y * v.y;
    #pragma unroll
    for (int m = 32; m; m >>= 1) ss += __shfl_xor(ss, m);
    const float inv = 1.0f / fmaxf(sqrtf(ss), 1e-12f);
    float bk;
    const float ox = v.x * inv, oy = v.y * inv;
    sh[2 * l] = f2bf(ox, bk);     sl[2 * l] = f2bf(ox - bk, bk);
    sh[2 * l + 1] = f2bf(oy, bk); sl[2 * l + 1] = f2bf(oy - bk, bk);
    __syncthreads();
    if (l < 32) {
      const int split = l >> 4, kc = (l >> 1) & 7, kh = l & 1;
      const short* src = (split ? sl : sh) + kc * 16 + kh * 8;
      const short8 val = *(const short8*)src;
      const size_t idx = (size_t)(row >> 5) * 4096 + kc * 512 +
                         ((row & 31) + 32 * kh) * 8;
      *(short8*)((split ? eLo : eHi) + idx) = val;
    }
  }
}

// ---------------- K1: h = x @ W^T + b, 8-way K-split, deep-pipelined -----------
// grid 512 (32-row tiles), 512 threads = 8 waves = 8 K-eighths (256 k each).
// A direct from global x (convert in-reg), B from packed wHi/wLo (L2).
// Epilogue: 4-buffer LDS reduce (2 barriers) + bias + bf16-split pack.
__global__ __launch_bounds__(512, 4) void k1_fused(const float* __restrict__ x,
                                                   const short* __restrict__ wHi,
                                                   const short* __restrict__ wLo,
                                                   const float* __restrict__ bias,
                                                   short* __restrict__ hHi,
                                                   short* __restrict__ hLo) {
  __shared__ __align__(16) float hs[4][32][132];   // 67.6 KB
  __shared__ float bsh[128];
  const int t = threadIdx.x;
  const int wave = t >> 6, lane = t & 63;
  const int fr = lane & 31, ks = lane >> 5;
  const int m0 = blockIdx.x * 32;

  if (t < 128) bsh[t] = bias[t];

  // wave's K-eighth: k in [wave*256, wave*256+256), 16 chunks of 16
  const float* xp = x + (size_t)(m0 + fr) * DM + wave * 256 + ks * 8;
  const short8* bhp = (const short8*)wHi + (size_t)wave * 16 * 64 + lane;
  const short8* blp = (const short8*)wLo + (size_t)wave * 16 * 64 + lane;

  f32x16 acc[4] = {};

  #pragma unroll
  for (int c = 0; c < 16; ++c) {
    const float4 a0 = *(const float4*)(xp + c * 16);
    const float4 a1 = *(const float4*)(xp + c * 16 + 4);
    const float av[8] = {a0.x, a0.y, a0.z, a0.w, a1.x, a1.y, a1.z, a1.w};
    short8 ah, al; float bk;
    #pragma unroll
    for (int e = 0; e < 8; ++e) {
      ah[e] = f2bf(av[e], bk); al[e] = f2bf(av[e] - bk, bk);
    }
    #pragma unroll
    for (int t2 = 0; t2 < 4; ++t2) {
      const short8 bh = bhp[(size_t)t2 * 8192 + c * 64];
      const short8 bl = blp[(size_t)t2 * 8192 + c * 64];
      acc[t2] = __builtin_amdgcn_mfma_f32_32x32x16_bf16(ah, bh, acc[t2], 0, 0, 0);
      acc[t2] = __builtin_amdgcn_mfma_f32_32x32x16_bf16(ah, bl, acc[t2], 0, 0, 0);
      acc[t2] = __builtin_amdgcn_mfma_f32_32x32x16_bf16(al, bh, acc[t2], 0, 0, 0);
    }
  }

  // ---- cross-wave K-reduction: waves 0-3 write bufs 0-3; waves 4-7 add ----
  if (wave < 4) {
    #pragma unroll
    for (int t2 = 0; t2 < 4; ++t2)
      #pragma unroll
      for (int reg = 0; reg < 16; ++reg) {
        const int row = (reg & 3) + 8 * (reg >> 2) + 4 * ks;
        hs[wave][row][t2 * 32 + fr] = acc[t2][reg];
      }
  }
  __syncthreads();
  if (wave >= 4) {
    #pragma unroll
    for (int t2 = 0; t2 < 4; ++t2)
      #pragma unroll
      for (int reg = 0; reg < 16; ++reg) {
        const int row = (reg & 3) + 8 * (reg >> 2) + 4 * ks;
        hs[wave - 4][row][t2 * 32 + fr] += acc[t2][reg];
      }
  }
  __syncthreads();

  // ---- pack: 512 tasks (row, 8k-group), 1 per thread ----
  {
    const int row = t >> 4, kc8 = t & 15;
    float v[8];
    #pragma unroll
    for (int j = 0; j < 8; ++j) {
      v[j] = ((hs[0][row][kc8 * 8 + j] + hs[1][row][kc8 * 8 + j]) +
              (hs[2][row][kc8 * 8 + j] + hs[3][row][kc8 * 8 + j])) +
             bsh[kc8 * 8 + j];
    }
    short8 hi8, lo8; float bk;
    #pragma unroll
    for (int e = 0; e < 8; ++e) {
      hi8[e] = f2bf(v[e], bk); lo8[e] = f2bf(v[e] - bk, bk);
    }
    const int kc = kc8 >> 1, kh = kc8 & 1;
    const size_t idx = (size_t)blockIdx.x * 512 + kc * 64 + (row + 32 * kh);
    ((short8*)hHi)[idx] = hi8;
    ((short8*)hLo)[idx] = lo8;
  }
}

// ---------------- K2: logits via MFMA + softmax + weighted col-sum -------------
// grid (256 row-tiles of 64, 3 segments), 512 threads = 8 waves. (verified)
__global__ __launch_bounds__(512, 2) void k2_mfma(const short* __restrict__ hHi,
                                                  const short* __restrict__ hLo,
                                                  const short* __restrict__ eHi,
                                                  const short* __restrict__ eLo,
                                                  const float* __restrict__ imp,
                                                  float* __restrict__ partials) {
  const int t = threadIdx.x;
  const int m0 = blockIdx.x * 64;
  const int seg = blockIdx.y;
  const int wave = t >> 6, lane = t & 63;
  const int wr = wave >> 2;
  const int wc = wave & 3;
  const int fr = lane & 31;
  const int hi = lane >> 5;

  __shared__ float redA[2][32][4];
  __shared__ float redB[2][32][4];
  __shared__ float ldsD[2][512];

  f32x16 acc[4] = {};

  const short8* pAh = (const short8*)hHi + ((m0 >> 5) + wr) * 512 + lane;
  const short8* pAl = (const short8*)hLo + ((m0 >> 5) + wr) * 512 + lane;
  const short8* pBh = (const short8*)eHi + (seg * 16 + wc * 4) * 512 + lane;
  const short8* pBl = (const short8*)eLo + (seg * 16 + wc * 4) * 512 + lane;

  #pragma unroll
  for (int kc = 0; kc < 8; ++kc) {
    const short8 ah = pAh[kc * 64];
    const short8 al = pAl[kc * 64];
    #pragma unroll
    for (int t2 = 0; t2 < 4; ++t2) {
      const short8 bh = pBh[t2 * 512 + kc * 64];
      const short8 bl = pBl[t2 * 512 + kc * 64];
      acc[t2] = __builtin_amdgcn_mfma_f32_32x32x16_bf16(ah, bh, acc[t2], 0, 0, 0);
      acc[t2] = __builtin_amdgcn_mfma_f32_32x32x16_bf16(ah, bl, acc[t2], 0, 0, 0);
      acc[t2] = __builtin_amdgcn_mfma_f32_32x32x16_bf16(al, bh, acc[t2], 0, 0, 0);
    }
  }

  // ---- row max (over 512 neurons) ----
  float mx[16];
  #pragma unroll
  for (int r = 0; r < 16; ++r) {
    float m = fmaxf(fmaxf(acc[0][r], acc[1][r]), fmaxf(acc[2][r], acc[3][r]));
    #pragma unroll
    for (int k = 1; k < 32; k <<= 1) m = fmaxf(m, __shfl_xor(m, k));
    mx[r] = m;
  }
  if (fr == 0) {
    #pragma unroll
    for (int r = 0; r < 16; ++r)
      redA[wr][(r & 3) + 8 * (r >> 2) + 4 * hi][wc] = mx[r];
  }
  __syncthreads();
  float M[16];
  #pragma unroll
  for (int r = 0; r < 16; ++r) {
    const int row = (r & 3) + 8 * (r >> 2) + 4 * hi;
    M[r] = fmaxf(fmaxf(redA[wr][row][0], redA[wr][row][1]),
                 fmaxf(redA[wr][row][2], redA[wr][row][3]));
  }

  // ---- exp + row sum ----
  float sm[16];
  #pragma unroll
  for (int r = 0; r < 16; ++r) {
    float s = 0.0f;
    #pragma unroll
    for (int t2 = 0; t2 < 4; ++t2) {
      const float p = __expf(acc[t2][r] - M[r]);
      acc[t2][r] = p;
      s += p;
    }
    #pragma unroll
    for (int k = 1; k < 32; k <<= 1) s += __shfl_xor(s, k);
    sm[r] = s;
  }
  if (fr == 0) {
    #pragma unroll
    for (int r = 0; r < 16; ++r)
      redB[wr][(r & 3) + 8 * (r >> 2) + 4 * hi][wc] = sm[r];
  }
  __syncthreads();
  float w[16];
  #pragma unroll
  for (int r = 0; r < 16; ++r) {
    const int row = (r & 3) + 8 * (r >> 2) + 4 * hi;
    const float S = (redB[wr][row][0] + redB[wr][row][1]) +
                    (redB[wr][row][2] + redB[wr][row][3]);
    w[r] = imp[m0 + wr * 32 + row] / S;
  }

  // ---- importance-weighted column partials (deterministic) ----
  #pragma unroll
  for (int t2 = 0; t2 < 4; ++t2) {
    float d = 0.0f;
    #pragma unroll
    for (int r = 0; r < 16; ++r) d = fmaf(acc[t2][r], w[r], d);
    d += __shfl_xor(d, 32);
    if (hi == 0) ldsD[wr][wc * 128 + t2 * 32 + fr] = d;
  }
  __syncthreads();
  partials[((size_t)seg * 256 + blockIdx.x) * 512 + t] = ldsD[0][t] + ldsD[1][t];
}

// ---------------- K3: sum partials (fixed order) + top-k + write ---------------
__global__ __launch_bounds__(256) void k3_topk(const float* __restrict__ partials,
                                               float* __restrict__ out) {
  const int b = blockIdx.x;
  const int seg = blockIdx.y;
  const int tid = threadIdx.x;
  const int K = (seg == 0) ? 8 : ((seg == 1) ? 4 : 6);

  __shared__ float v[512];
  __shared__ float wv[8];
  __shared__ int wi[8];
  __shared__ float redv[4];
  __shared__ int redi[4];

  const float* src = partials + ((size_t)seg * 256 + b * 64) * 512;
  float a0 = 0.f, a1 = 0.f, a2 = 0.f, a3 = 0.f;
  float b0 = 0.f, b1 = 0.f, b2 = 0.f, b3 = 0.f;
  for (int j = 0; j < 64; j += 4) {
    a0 += src[(size_t)(j + 0) * 512 + tid];
    a1 += src[(size_t)(j + 1) * 512 + tid];
    a2 += src[(size_t)(j + 2) * 512 + tid];
    a3 += src[(size_t)(j + 3) * 512 + tid];
    b0 += src[(size_t)(j + 0) * 512 + tid + 256];
    b1 += src[(size_t)(j + 1) * 512 + tid + 256];
    b2 += src[(size_t)(j + 2) * 512 + tid + 256];
    b3 += src[(size_t)(j + 3) * 512 + tid + 256];
  }
  v[tid] = (a0 + a1) + (a2 + a3);
  v[tid + 256] = (b0 + b1) + (b2 + b3);
  __syncthreads();

  for (int t = 0; t < K; ++t) {
    const float v0 = v[tid], v1 = v[tid + 256];
    float bv; int bi;
    if (v1 > v0) { bv = v1; bi = tid + 256; } else { bv = v0; bi = tid; }
    #pragma unroll
    for (int m = 1; m < 64; m <<= 1) {
      const float ov = __shfl_xor(bv, m);
      const int oi = __shfl_xor(bi, m);
      if (ov > bv || (ov == bv && oi < bi)) { bv = ov; bi = oi; }
    }
    if ((tid & 63) == 0) { redv[tid >> 6] = bv; redi[tid >> 6] = bi; }
    __syncthreads();
    if (tid == 0) {
      float best = redv[0]; int besti = redi[0];
      for (int q = 1; q < 4; ++q)
        if (redv[q] > best || (redv[q] == best && redi[q] < besti)) {
          best = redv[q]; besti = redi[q];
        }
      wv[t] = best; wi[t] = besti;
      v[besti] = -3.0e38f;
    }
    __syncthreads();
  }

  float s = 1e-8f;
  for (int t = 0; t < K; ++t) s += wv[t];

  const int slot0 = (seg == 0) ? 0 : ((seg == 1) ? 1 : 3);
  float* o0 = out + slot0 * (BATCH * NSEG) + b * NSEG;
  o0[tid] = 0.0f; o0[tid + 256] = 0.0f;
  float* o1 = nullptr;
  if (seg == 1) {
    o1 = out + 2 * (BATCH * NSEG) + b * NSEG;
    o1[tid] = 0.0f; o1[tid + 256] = 0.0f;
  }
  __syncthreads();
  if (tid < K) {
    const float val = wv[tid] / s;
    o0[wi[tid]] = val;
    if (seg == 1) o1[wi[tid]] = val;
  }
}

// -------------------------------- launch ---------------------------------------
extern "C" void kernel_launch(void* const* d_in, const int* in_sizes, int n_in,
                              void* d_out, int out_size, void* d_ws, size_t ws_size,
                              hipStream_t stream) {
  (void)in_sizes; (void)n_in; (void)out_size; (void)ws_size;
  const float* x    = (const float*)d_in[0];
  const float* imp  = (const float*)d_in[1];
  const float* W    = (const float*)d_in[2];
  const float* bias = (const float*)d_in[3];
  const float* emb  = (const float*)d_in[4];
  float* out = (float*)d_out;

  // workspace carve: partials (f32), then hHi | hLo | eHi | eLo | wHi | wLo (i16)
  float* partials = (float*)d_ws;                     // 768*512 f32
  short* hHi      = (short*)(partials + 768 * 512);   // 2097152 i16
  short* hLo      = hHi + 2097152;
  short* eHi      = hLo + 2097152;                    // 196608 i16
  short* eLo      = eHi + 196608;
  short* wHi      = eLo + 196608;                     // 262144 i16
  short* wLo      = wHi + 262144;

  k0_prep<<<512 + 1536, 64, 0, stream>>>(W, emb, wHi, wLo, eHi, eLo);
  k1_fused<<<ROWS / 32, 512, 0, stream>>>(x, wHi, wLo, bias, hHi, hLo);
  k2_mfma<<<dim3(ROWS / 64, 3), 512, 0, stream>>>(hHi, hLo, eHi, eLo, imp, partials);
  k3_topk<<<dim3(BATCH, 3), 256, 0, stream>>>(partials, out);
}